// Round 17
// baseline (69.172 us; speedup 1.0000x reference)
//
#include <hip/hip_runtime.h>

using u16 = unsigned short;
using u32 = unsigned int;
using u64 = unsigned long long;

typedef short bf16x8 __attribute__((ext_vector_type(8)));
typedef float f32x4 __attribute__((ext_vector_type(4)));

static constexpr int NB  = 4;     // batch
static constexpr int NN  = 4096;  // nodes
static constexpr int KIN = 256;   // in features
static constexpr int FO  = 128;   // out features
static constexpr int NROW = NB * NN;  // 16384 total rows
static constexpr int NCC = 64;    // coarse chunks per batch (64 positions each)
static constexpr int NWK = 248;   // persistent GEMM workers in kB
static constexpr float SLOPE = 0.01f;

// ---- bf16 helpers (RNE, no NaN inputs) ----
__device__ __forceinline__ u16 f2bf(float f) {
  const u32 u = __float_as_uint(f);
  return (u16)((u + 0x7fffu + ((u >> 16) & 1u)) >> 16);
}
__device__ __forceinline__ float bf2f(u16 h) {
  return __uint_as_float(((u32)h) << 16);
}
__device__ __forceinline__ float dot4(const float4& a, const float4& b) {
  return a.x * b.x + a.y * b.y + a.z * b.z + a.w * b.w;
}

// monotone bijection f32 -> orderable u32 (no NaNs present)
__device__ __forceinline__ u32 f2key(float f) {
  const u32 b = __float_as_uint(f);
  return (b & 0x80000000u) ? ~b : (b | 0x80000000u);
}
__device__ __forceinline__ float key2f(u32 u) {
  const u32 b = (u & 0x80000000u) ? (u ^ 0x80000000u) : ~u;
  return __uint_as_float(b);
}

__device__ __forceinline__ u64 shfl_xor64(u64 v, int m) {
  const u32 lo = __shfl_xor((u32)(v & 0xffffffffu), m, 64);
  const u32 hi = __shfl_xor((u32)(v >> 32), m, 64);
  return ((u64)hi << 32) | (u64)lo;
}
__device__ __forceinline__ void cswap(u64& a, u64& b, bool up) {
  if ((a > b) == up) { const u64 tmp = a; a = b; b = tmp; }
}

// bitonic rounds j = min(k/2,128)..1 for phase k, data in registers.
__device__ __forceinline__ void reg_session(u64 e[4], int t, int k) {
  const int jstart = (k > 256) ? 128 : (k >> 1);
  for (int j = jstart; j >= 4; j >>= 1) {
    const int J = j >> 2;
    const bool up   = ((t & (k >> 2)) == 0);
    const bool lowr = ((t & J) == 0);
#pragma unroll
    for (int r = 0; r < 4; ++r) {
      const u64 o = shfl_xor64(e[r], J);
      const bool less = e[r] < o;              // keys unique (idx tie-break)
      e[r] = ((lowr == up) == less) ? e[r] : o;
    }
  }
  if (k >= 4) {
    const bool up = ((t & (k >> 2)) == 0);
    cswap(e[0], e[2], up); cswap(e[1], e[3], up);
  }
  {
    const bool up0 = (((4 * t)     & k) == 0);
    const bool up1 = (((4 * t + 2) & k) == 0);
    cswap(e[0], e[1], up0); cswap(e[2], e[3], up1);
  }
}

__device__ __forceinline__ int lower_bound_s(const float* a, int n, float t) {
  int lo = 0, hi = n;
  while (lo < hi) {
    const int mid = (lo + hi) >> 1;
    if (a[mid] < t) lo = mid + 1; else hi = mid;
  }
  return lo;
}

// ---------------- Kernel 0: W split + exact f1/f2 (pre-GEMM) ---------------
// grid 256 x 256. Every block: u_l/u_r in LDS (thread t = k-row), then
// f1/f2 for 64 rows (wave per 16 rows, lane-parallel dot + shfl reduce).
// Blocks 0-63 additionally write the Wh/Wl bf16 transposed split.
__global__ __launch_bounds__(256) void k0_prep(const float* __restrict__ x,
                                               const float* __restrict__ W,
                                               const float* __restrict__ wl,
                                               const float* __restrict__ blp,
                                               const float* __restrict__ wr,
                                               const float* __restrict__ brp,
                                               u16* __restrict__ whT,
                                               u16* __restrict__ wloT,
                                               float* __restrict__ f1g,
                                               float* __restrict__ f2g) {
  __shared__ float uls[KIN];
  __shared__ float urs[KIN];
  const int t = threadIdx.x;
  const int bid = blockIdx.x;

  if (bid < 64) {  // W hi/lo split transpose
#pragma unroll
    for (int e = 0; e < 2; ++e) {
      const int idx = bid * 512 + t + e * 256;  // 0..32767
      const int col = idx >> 8, k = idx & 255;
      const float v = W[k * FO + col];
      const u16 h = f2bf(v);
      whT[col * KIN + k]  = h;
      wloT[col * KIN + k] = f2bf(v - bf2f(h));
    }
  }
  // u_l[k]/u_r[k] for k = t (exact f32 serial dot; W L2-hot)
  {
    const float* Wr = W + (size_t)t * FO;
    float s1 = 0.f, s2 = 0.f;
#pragma unroll 8
    for (int c = 0; c < FO; ++c) {
      const float wv = Wr[c];
      s1 = fmaf(wv, wl[c], s1);
      s2 = fmaf(wv, wr[c], s2);
    }
    uls[t] = s1; urs[t] = s2;
  }
  __syncthreads();
  // f1/f2: wave wv handles 16 rows serially; 64 lanes x float4 covers a row
  const int wv = t >> 6, lane = t & 63;
  const int row0 = bid * 64 + wv * 16;
  const float4 ul = *(const float4*)(&uls[lane * 4]);
  const float4 ur = *(const float4*)(&urs[lane * 4]);
  const float blv = blp[0], brv = brp[0];
  for (int r = 0; r < 16; ++r) {
    const int row = row0 + r;
    const float4 xv = *(const float4*)(x + (size_t)row * KIN + lane * 4);
    float d1 = dot4(xv, ul);
    float d2 = dot4(xv, ur);
#pragma unroll
    for (int off = 1; off < 64; off <<= 1) {
      d1 += __shfl_xor(d1, off, 64);
      d2 += __shfl_xor(d2, off, 64);
    }
    if (lane == 0) { f1g[row] = d1 + blv; f2g[row] = d2 + brv; }
  }
}

// ---------------- Kernel B: sort (blocks 0-7) || persistent MFMA GEMM ------
// grid 256 x 1024. Sort path: R8 k3a verbatim. GEMM path: 248 workers loop
// over 256 tiles (BM=64, 16 waves 4x4, wave-tile 16x32, split-bf16 MFMA).
__global__ __launch_bounds__(1024, 1) void kB_main(const float* __restrict__ x,
                                                   const u16* __restrict__ whT,
                                                   const u16* __restrict__ wloT,
                                                   const float* __restrict__ f1g,
                                                   const float* __restrict__ f2g,
                                                   float* __restrict__ feats,
                                                   float* __restrict__ f1sort,
                                                   float* __restrict__ sc1,
                                                   float* __restrict__ sc2,
                                                   float* __restrict__ f2sort,
                                                   int* __restrict__ jidxS) {
  __shared__ __align__(16) unsigned char smem[55296];
  const int tid = threadIdx.x;
  const int bid = blockIdx.x;

  if (bid < 8) {
    // ======== hierarchical bitonic sort + exp scans (R8 k3a) ========
    u64* lds = (u64*)smem;                  // [4096] = 32 KiB
    float* wsumA = (float*)(smem + 32768);  // [16]
    float* wsumB = (float*)(smem + 32832);  // [16]
    const int t = tid;
    const int lane = t & 63, wv = t >> 6;
    const int b = bid & 3;
    const int task = bid >> 2;
    const int base = b * NN;
    const float* __restrict__ src = task ? f2g : f1g;

    u64 e[4];
#pragma unroll
    for (int r = 0; r < 4; ++r) {
      const int i = 4 * t + r;
      e[r] = ((u64)f2key(src[base + i]) << 32) | (u32)i;
    }
    for (int k = 2; k <= 256; k <<= 1) reg_session(e, t, k);
#pragma unroll
    for (int r = 0; r < 4; ++r) lds[4 * t + r] = e[r];
    __syncthreads();
    for (int k = 512; k <= NN; k <<= 1) {
      for (int j = k >> 1; j >= 256; j >>= 1) {
#pragma unroll
        for (int pp = 0; pp < 2; ++pp) {
          const int pw = t + pp * 1024;
          const int i = ((pw & ~(j - 1)) << 1) | (pw & (j - 1));
          const int ix = i | j;
          const bool up = ((i & k) == 0);
          const u64 a = lds[i], c = lds[ix];
          if ((a > c) == up) { lds[i] = c; lds[ix] = a; }
        }
        __syncthreads();
      }
#pragma unroll
      for (int r = 0; r < 4; ++r) e[r] = lds[4 * t + r];
      reg_session(e, t, k);
      if (k < NN) {
#pragma unroll
        for (int r = 0; r < 4; ++r) lds[4 * t + r] = e[r];
        __syncthreads();
      }
    }
    if (task == 0) {
      float kf[4], a[4], c[4];
#pragma unroll
      for (int r = 0; r < 4; ++r) {
        kf[r] = key2f((u32)(e[r] >> 32));
        f1sort[base + 4 * t + r] = kf[r];
        a[r] = expf(kf[r]);
        c[r] = expf(SLOPE * kf[r]);
      }
#pragma unroll
      for (int r = 1; r < 4; ++r) { a[r] += a[r - 1]; c[r] += c[r - 1]; }
      const float sa = a[3], sb = c[3];
      float pa = sa, pb = sb;
      for (int off = 1; off < 64; off <<= 1) {
        const float oa = __shfl_up(pa, off, 64);
        const float ob = __shfl_up(pb, off, 64);
        if (lane >= off) { pa += oa; pb += ob; }
      }
      if (lane == 63) { wsumA[wv] = pa; wsumB[wv] = pb; }
      __syncthreads();
      float wpa = 0.f, wpb = 0.f;
      for (int w2 = 0; w2 < wv; ++w2) { wpa += wsumA[w2]; wpb += wsumB[w2]; }
      const float basea = wpa + pa - sa, baseb = wpb + pb - sb;
#pragma unroll
      for (int r = 0; r < 4; ++r) {
        sc1[base + 4 * t + r] = basea + a[r];
        sc2[base + 4 * t + r] = baseb + c[r];
      }
    } else {
#pragma unroll
      for (int r = 0; r < 4; ++r) {
        f2sort[base + 4 * t + r] = key2f((u32)(e[r] >> 32));
        jidxS[base + 4 * t + r]  = (int)(e[r] & 0xffffffffu);
      }
    }
  } else {
    // ======== persistent split-bf16 MFMA GEMM (248 workers, 256 tiles) =====
    u16* axh = (u16*)smem;                 // [64][72]
    u16* axl = (u16*)(smem + 9216);
    u16* bwh = (u16*)(smem + 18432);       // [128][72]
    u16* bwl = (u16*)(smem + 36864);
    const int w = tid >> 6, lane = tid & 63;
    const int wm = w >> 2, wn = w & 3;
    const int xr = tid >> 4, xc4 = (tid & 15) * 4;   // x staging: 64r x 16 f4
    const int wcol = tid >> 3, wc = tid & 7;         // W staging: 128c x 8 b8
    bool needSync = false;

    for (int tile = bid - 8; tile < NROW / 64; tile += NWK) {
      const int row0 = tile * 64;
      f32x4 acc[2];
      acc[0] = (f32x4)0.f; acc[1] = (f32x4)0.f;
      float4 xv;
      bf16x8 whb, wlb;
      xv  = *(const float4*)(x + (size_t)(row0 + xr) * KIN + xc4);
      whb = *(const bf16x8*)(whT  + (size_t)wcol * KIN + wc * 8);
      wlb = *(const bf16x8*)(wloT + (size_t)wcol * KIN + wc * 8);

      for (int it = 0; it < 4; ++it) {
        if (it || needSync) __syncthreads();
        {
          float va[4] = {xv.x, xv.y, xv.z, xv.w};
          ushort4 hh, ll;
          const u16 h0 = f2bf(va[0]); hh.x = h0; ll.x = f2bf(va[0] - bf2f(h0));
          const u16 h1 = f2bf(va[1]); hh.y = h1; ll.y = f2bf(va[1] - bf2f(h1));
          const u16 h2 = f2bf(va[2]); hh.z = h2; ll.z = f2bf(va[2] - bf2f(h2));
          const u16 h3 = f2bf(va[3]); hh.w = h3; ll.w = f2bf(va[3] - bf2f(h3));
          *(ushort4*)(&axh[xr * 72 + xc4]) = hh;
          *(ushort4*)(&axl[xr * 72 + xc4]) = ll;
        }
        *(bf16x8*)(&bwh[wcol * 72 + wc * 8]) = whb;
        *(bf16x8*)(&bwl[wcol * 72 + wc * 8]) = wlb;
        __syncthreads();
        if (it < 3) {  // prefetch next k-chunk (overlaps MFMA)
          xv  = *(const float4*)(x + (size_t)(row0 + xr) * KIN + (it + 1) * 64 + xc4);
          whb = *(const bf16x8*)(whT  + (size_t)wcol * KIN + (it + 1) * 64 + wc * 8);
          wlb = *(const bf16x8*)(wloT + (size_t)wcol * KIN + (it + 1) * 64 + wc * 8);
        }
#pragma unroll
        for (int kk = 0; kk < 2; ++kk) {
          const int kb = kk * 32 + (lane >> 4) * 8;
          const int ar = wm * 16 + (lane & 15);
          const bf16x8 ah = *(const bf16x8*)(&axh[ar * 72 + kb]);
          const bf16x8 al = *(const bf16x8*)(&axl[ar * 72 + kb]);
#pragma unroll
          for (int n = 0; n < 2; ++n) {
            const int cidx = wn * 32 + n * 16 + (lane & 15);
            const bf16x8 bh  = *(const bf16x8*)(&bwh[cidx * 72 + kb]);
            const bf16x8 blo = *(const bf16x8*)(&bwl[cidx * 72 + kb]);
            acc[n] = __builtin_amdgcn_mfma_f32_16x16x32_bf16(ah, bh,  acc[n], 0, 0, 0);
            acc[n] = __builtin_amdgcn_mfma_f32_16x16x32_bf16(ah, blo, acc[n], 0, 0, 0);
            acc[n] = __builtin_amdgcn_mfma_f32_16x16x32_bf16(al, bh,  acc[n], 0, 0, 0);
          }
        }
      }
      needSync = true;
      // epilogue: C map col=lane&15, row=(lane>>4)*4+r
      const int rb = row0 + wm * 16 + (lane >> 4) * 4;
      const int cb = wn * 32 + (lane & 15);
#pragma unroll
      for (int n = 0; n < 2; ++n)
#pragma unroll
        for (int r = 0; r < 4; ++r)
          feats[(size_t)(rb + r) * FO + cb + n * 16] = acc[n][r];
    }
  }
}

// ---------------- Kernel 3b: alpha/beta per sorted-j, kpos/E1/E2 per row ----
__global__ __launch_bounds__(512) void k3b_ab(const float* __restrict__ f1sort,
                                              const float* __restrict__ sc1,
                                              const float* __restrict__ sc2,
                                              const float* __restrict__ f2sort,
                                              const float* __restrict__ f1g,
                                              float* __restrict__ alphaS,
                                              float* __restrict__ betaS,
                                              int* __restrict__ kposA,
                                              float* __restrict__ E1g,
                                              float* __restrict__ E2g) {
  __shared__ float s_f1[NN];  // 16 KiB
  __shared__ float s_f2[NN];  // 16 KiB
  const int b = blockIdx.x >> 3;
  const int part = blockIdx.x & 7;
  const int base = b * NN;
  for (int i = threadIdx.x; i < NN; i += 512) {
    s_f1[i] = f1sort[base + i];
    s_f2[i] = f2sort[base + i];
  }
  __syncthreads();
  const int g = part * 512 + threadIdx.x;
  const float T1 = sc1[base + NN - 1];
  const float f1max = s_f1[NN - 1];
  {
    const float f2v = s_f2[g];
    const float m = f1max + f2v;
    const float M = (m >= 0.f) ? m : SLOPE * m;      // column max of leaky scores
    const int p = lower_bound_s(s_f1, NN, -f2v);     // first i with f1 >= -f2
    const float S1 = T1 - (p > 0 ? sc1[base + p - 1] : 0.f);
    const float S2 = (p > 0 ? sc2[base + p - 1] : 0.f);
    const float ea = expf(f2v - M);
    const float eb = expf(SLOPE * f2v - M);
    const float invD = 1.0f / (ea * S1 + eb * S2);
    alphaS[base + g] = ea * invD;
    betaS[base + g]  = eb * invD;
  }
  {
    const float f1v = f1g[base + g];
    kposA[base + g] = lower_bound_s(s_f2, NN, -f1v); // first sorted-j with f2 >= -f1
    E1g[base + g] = expf(f1v);
    E2g[base + g] = expf(SLOPE * f1v);
  }
}

// ---------------- Kernel 4a: per-position inclusive prefixes + chunk totals -
__global__ __launch_bounds__(128) void k4a_pref(const float* __restrict__ feats,
                                                const float* __restrict__ alphaS,
                                                const float* __restrict__ betaS,
                                                const int* __restrict__ jidxS,
                                                float* __restrict__ finePreA,
                                                float* __restrict__ finePreB,
                                                float* __restrict__ csumA,
                                                float* __restrict__ csumB) {
  const int b = blockIdx.x >> 6, cc = blockIdx.x & 63;
  const int o = threadIdx.x;
  const int base = b * NN + cc * 64;
  const float* fb = feats + (size_t)b * NN * FO;
  float accA = 0.f, accB = 0.f;
#pragma unroll 8
  for (int q = 0; q < 64; ++q) {
    const int kk = base + q;
    const int j = jidxS[kk];
    const float fv = fb[(size_t)j * FO + o];
    accA = fmaf(alphaS[kk], fv, accA);
    accB = fmaf(betaS[kk], fv, accB);
    finePreA[(size_t)kk * FO + o] = accA;
    finePreB[(size_t)kk * FO + o] = accB;
  }
  csumA[(size_t)(b * NCC + cc) * FO + o] = accA;   // compact chunk totals
  csumB[(size_t)(b * NCC + cc) * FO + o] = accB;
}

// ---------------- Kernel 4c: parallel exclusive scan over chunk sums --------
// grid NB*8 x 1024: block = (batch, 16-col group). Hillis-Steele over 64
// chunks in LDS (padded [64][17] -> no bank conflicts).
__global__ __launch_bounds__(1024) void k4c_coar(const float* __restrict__ csumA,
                                                 const float* __restrict__ csumB,
                                                 float* __restrict__ coarA,
                                                 float* __restrict__ coarB) {
  __shared__ float sA[64][17];
  __shared__ float sB[64][17];
  const int b = blockIdx.x >> 3, g = blockIdx.x & 7;
  const int t = threadIdx.x;
  const int c = t & 63, ol = t >> 6;     // c = chunk, ol = 0..15
  const int o = g * 16 + ol;
  sA[c][ol] = csumA[(size_t)(b * NCC + c) * FO + o];
  sB[c][ol] = csumB[(size_t)(b * NCC + c) * FO + o];
  __syncthreads();
#pragma unroll
  for (int d = 1; d < 64; d <<= 1) {
    const float tA = (c >= d) ? sA[c - d][ol] : 0.f;
    const float tB = (c >= d) ? sB[c - d][ol] : 0.f;
    __syncthreads();
    sA[c][ol] += tA; sB[c][ol] += tB;
    __syncthreads();
  }
  const float exA = (c == 0) ? 0.f : sA[c - 1][ol];
  const float exB = (c == 0) ? 0.f : sB[c - 1][ol];
  coarA[(size_t)(b * (NCC + 1) + c) * FO + o] = exA;
  coarB[(size_t)(b * (NCC + 1) + c) * FO + o] = exB;
  if (c == 63) {
    coarA[(size_t)(b * (NCC + 1) + NCC) * FO + o] = sA[63][ol];  // total
    coarB[(size_t)(b * (NCC + 1) + NCC) * FO + o] = sB[63][ol];
  }
}

// ---------------- Kernel 5: streaming combine (no gathers) ------------------
__global__ __launch_bounds__(256) void k5_out(const float* __restrict__ finePreA,
                                              const float* __restrict__ finePreB,
                                              const float* __restrict__ coarA,
                                              const float* __restrict__ coarB,
                                              const int* __restrict__ kposA,
                                              const float* __restrict__ E1g,
                                              const float* __restrict__ E2g,
                                              float* __restrict__ out) {
  const int t = threadIdx.x;
  const int row = blockIdx.x * 2 + (t >> 7);
  const int o = t & 127;
  const int b = row >> 12;  // NN = 4096
  const int kp = kposA[row];
  const float e1 = E1g[row], e2 = E2g[row];
  const int c = kp >> 6;          // 0..64

  float runA = coarA[(size_t)(b * (NCC + 1) + c) * FO + o];
  float runB = coarB[(size_t)(b * (NCC + 1) + c) * FO + o];
  const float totA = coarA[(size_t)(b * (NCC + 1) + NCC) * FO + o];
  if (kp & 63) {
    runA += finePreA[(size_t)(b * NN + kp - 1) * FO + o];
    runB += finePreB[(size_t)(b * NN + kp - 1) * FO + o];
  }
  out[(size_t)row * FO + o] = fmaf(e1, totA - runA, e2 * runB);
}

extern "C" void kernel_launch(void* const* d_in, const int* in_sizes, int n_in,
                              void* d_out, int out_size, void* d_ws, size_t ws_size,
                              hipStream_t stream) {
  const float* x  = (const float*)d_in[0];
  const float* W  = (const float*)d_in[1];
  const float* wl = (const float*)d_in[2];
  const float* bl = (const float*)d_in[3];
  const float* wr = (const float*)d_in[4];
  const float* br = (const float*)d_in[5];
  float* out = (float*)d_out;

  float* ws = (float*)d_ws;
  float* feats    = ws; ws += NROW * FO;
  float* finePreA = ws; ws += NROW * FO;
  float* finePreB = ws; ws += NROW * FO;
  float* f1g      = ws; ws += NROW;
  float* f2g      = ws; ws += NROW;
  float* f1sort   = ws; ws += NROW;
  float* f2sort   = ws; ws += NROW;
  float* sc1      = ws; ws += NROW;
  float* sc2      = ws; ws += NROW;
  float* alphaS   = ws; ws += NROW;
  float* betaS    = ws; ws += NROW;
  float* E1g      = ws; ws += NROW;
  float* E2g      = ws; ws += NROW;
  int* jidxS      = (int*)ws; ws += NROW;
  int* kposA      = (int*)ws; ws += NROW;
  float* coarA    = ws; ws += NB * (NCC + 1) * FO;
  float* coarB    = ws; ws += NB * (NCC + 1) * FO;
  float* csumA    = ws; ws += NB * NCC * FO;
  float* csumB    = ws; ws += NB * NCC * FO;
  u16* whT  = (u16*)ws; ws += FO * KIN / 2;     // bf16 [128 col][256 k]
  u16* wloT = (u16*)ws; ws += FO * KIN / 2;
  (void)in_sizes; (void)n_in; (void)out_size; (void)ws_size;

  hipLaunchKernelGGL(k0_prep,  dim3(NROW / 64), dim3(256),  0, stream,
                     x, W, wl, bl, wr, br, whT, wloT, f1g, f2g);
  hipLaunchKernelGGL(kB_main,  dim3(256),       dim3(1024), 0, stream,
                     x, whT, wloT, f1g, f2g, feats,
                     f1sort, sc1, sc2, f2sort, jidxS);
  hipLaunchKernelGGL(k3b_ab,   dim3(NB * 8),    dim3(512),  0, stream,
                     f1sort, sc1, sc2, f2sort, f1g, alphaS, betaS, kposA, E1g, E2g);
  hipLaunchKernelGGL(k4a_pref, dim3(NB * NCC),  dim3(128),  0, stream,
                     feats, alphaS, betaS, jidxS, finePreA, finePreB, csumA, csumB);
  hipLaunchKernelGGL(k4c_coar, dim3(NB * 8),    dim3(1024), 0, stream,
                     csumA, csumB, coarA, coarB);
  hipLaunchKernelGGL(k5_out,   dim3(NROW / 2),  dim3(256),  0, stream,
                     finePreA, finePreB, coarA, coarB, kposA, E1g, E2g, out);
}

// Round 18
// 67.890 us; speedup vs baseline: 1.0189x; 1.0189x over previous
//
#include <hip/hip_runtime.h>

using u16 = unsigned short;
using u32 = unsigned int;
using u64 = unsigned long long;

typedef short bf16x8 __attribute__((ext_vector_type(8)));
typedef float f32x4 __attribute__((ext_vector_type(4)));

static constexpr int NB  = 4;     // batch
static constexpr int NN  = 4096;  // nodes
static constexpr int KIN = 256;   // in features
static constexpr int FO  = 128;   // out features
static constexpr int NROW = NB * NN;  // 16384 total rows
static constexpr int NCC = 64;    // coarse chunks per batch (64 positions each)
static constexpr int NWK = 248;   // persistent GEMM workers in kB
static constexpr float SLOPE = 0.01f;

// ---- bf16 helpers (RNE, no NaN inputs) ----
__device__ __forceinline__ u16 f2bf(float f) {
  const u32 u = __float_as_uint(f);
  return (u16)((u + 0x7fffu + ((u >> 16) & 1u)) >> 16);
}
__device__ __forceinline__ float bf2f(u16 h) {
  return __uint_as_float(((u32)h) << 16);
}
__device__ __forceinline__ float dot4(const float4& a, const float4& b) {
  return a.x * b.x + a.y * b.y + a.z * b.z + a.w * b.w;
}

// monotone bijection f32 -> orderable u32 (no NaNs present)
__device__ __forceinline__ u32 f2key(float f) {
  const u32 b = __float_as_uint(f);
  return (b & 0x80000000u) ? ~b : (b | 0x80000000u);
}
__device__ __forceinline__ float key2f(u32 u) {
  const u32 b = (u & 0x80000000u) ? (u ^ 0x80000000u) : ~u;
  return __uint_as_float(b);
}

__device__ __forceinline__ u64 shfl_xor64(u64 v, int m) {
  const u32 lo = __shfl_xor((u32)(v & 0xffffffffu), m, 64);
  const u32 hi = __shfl_xor((u32)(v >> 32), m, 64);
  return ((u64)hi << 32) | (u64)lo;
}
__device__ __forceinline__ void cswap(u64& a, u64& b, bool up) {
  if ((a > b) == up) { const u64 tmp = a; a = b; b = tmp; }
}

// bitonic rounds j = min(k/2,128)..1 for phase k, data in registers.
__device__ __forceinline__ void reg_session(u64 e[4], int t, int k) {
  const int jstart = (k > 256) ? 128 : (k >> 1);
  for (int j = jstart; j >= 4; j >>= 1) {
    const int J = j >> 2;
    const bool up   = ((t & (k >> 2)) == 0);
    const bool lowr = ((t & J) == 0);
#pragma unroll
    for (int r = 0; r < 4; ++r) {
      const u64 o = shfl_xor64(e[r], J);
      const bool less = e[r] < o;              // keys unique (idx tie-break)
      e[r] = ((lowr == up) == less) ? e[r] : o;
    }
  }
  if (k >= 4) {
    const bool up = ((t & (k >> 2)) == 0);
    cswap(e[0], e[2], up); cswap(e[1], e[3], up);
  }
  {
    const bool up0 = (((4 * t)     & k) == 0);
    const bool up1 = (((4 * t + 2) & k) == 0);
    cswap(e[0], e[1], up0); cswap(e[2], e[3], up1);
  }
}

__device__ __forceinline__ int lower_bound_s(const float* a, int n, float t) {
  int lo = 0, hi = n;
  while (lo < hi) {
    const int mid = (lo + hi) >> 1;
    if (a[mid] < t) lo = mid + 1; else hi = mid;
  }
  return lo;
}

// ---------------- Kernel 0: W split + exact f1/f2 (pre-GEMM) ---------------
// grid 256 x 256. Every block: u_l/u_r in LDS (thread t = k-row), then
// f1/f2 for 64 rows (wave per 16 rows, lane-parallel dot + shfl reduce).
// Blocks 0-63 additionally write the Wh/Wl bf16 transposed split.
__global__ __launch_bounds__(256) void k0_prep(const float* __restrict__ x,
                                               const float* __restrict__ W,
                                               const float* __restrict__ wl,
                                               const float* __restrict__ blp,
                                               const float* __restrict__ wr,
                                               const float* __restrict__ brp,
                                               u16* __restrict__ whT,
                                               u16* __restrict__ wloT,
                                               float* __restrict__ f1g,
                                               float* __restrict__ f2g) {
  __shared__ float uls[KIN];
  __shared__ float urs[KIN];
  const int t = threadIdx.x;
  const int bid = blockIdx.x;

  if (bid < 64) {  // W hi/lo split transpose
#pragma unroll
    for (int e = 0; e < 2; ++e) {
      const int idx = bid * 512 + t + e * 256;  // 0..32767
      const int col = idx >> 8, k = idx & 255;
      const float v = W[k * FO + col];
      const u16 h = f2bf(v);
      whT[col * KIN + k]  = h;
      wloT[col * KIN + k] = f2bf(v - bf2f(h));
    }
  }
  // u_l[k]/u_r[k] for k = t (exact f32 serial dot; W L2-hot)
  {
    const float* Wr = W + (size_t)t * FO;
    float s1 = 0.f, s2 = 0.f;
#pragma unroll 8
    for (int c = 0; c < FO; ++c) {
      const float wv = Wr[c];
      s1 = fmaf(wv, wl[c], s1);
      s2 = fmaf(wv, wr[c], s2);
    }
    uls[t] = s1; urs[t] = s2;
  }
  __syncthreads();
  // f1/f2: wave wv handles 16 rows serially; 64 lanes x float4 covers a row
  const int wv = t >> 6, lane = t & 63;
  const int row0 = bid * 64 + wv * 16;
  const float4 ul = *(const float4*)(&uls[lane * 4]);
  const float4 ur = *(const float4*)(&urs[lane * 4]);
  const float blv = blp[0], brv = brp[0];
  for (int r = 0; r < 16; ++r) {
    const int row = row0 + r;
    const float4 xv = *(const float4*)(x + (size_t)row * KIN + lane * 4);
    float d1 = dot4(xv, ul);
    float d2 = dot4(xv, ur);
#pragma unroll
    for (int off = 1; off < 64; off <<= 1) {
      d1 += __shfl_xor(d1, off, 64);
      d2 += __shfl_xor(d2, off, 64);
    }
    if (lane == 0) { f1g[row] = d1 + blv; f2g[row] = d2 + brv; }
  }
}

// ---------------- Kernel B: sort (blocks 0-7) || persistent MFMA GEMM ------
// grid 256 x 1024. Sort path: R8 k3a verbatim. GEMM path: 248 workers loop
// over 256 tiles (BM=64, 16 waves 4x4, wave-tile 16x32, split-bf16 MFMA).
__global__ __launch_bounds__(1024, 1) void kB_main(const float* __restrict__ x,
                                                   const u16* __restrict__ whT,
                                                   const u16* __restrict__ wloT,
                                                   const float* __restrict__ f1g,
                                                   const float* __restrict__ f2g,
                                                   float* __restrict__ feats,
                                                   float* __restrict__ f1sort,
                                                   float* __restrict__ sc1,
                                                   float* __restrict__ sc2,
                                                   float* __restrict__ f2sort,
                                                   int* __restrict__ jidxS) {
  __shared__ __align__(16) unsigned char smem[55296];
  const int tid = threadIdx.x;
  const int bid = blockIdx.x;

  if (bid < 8) {
    // ======== hierarchical bitonic sort + exp scans (R8 k3a) ========
    u64* lds = (u64*)smem;                  // [4096] = 32 KiB
    float* wsumA = (float*)(smem + 32768);  // [16]
    float* wsumB = (float*)(smem + 32832);  // [16]
    const int t = tid;
    const int lane = t & 63, wv = t >> 6;
    const int b = bid & 3;
    const int task = bid >> 2;
    const int base = b * NN;
    const float* __restrict__ src = task ? f2g : f1g;

    u64 e[4];
#pragma unroll
    for (int r = 0; r < 4; ++r) {
      const int i = 4 * t + r;
      e[r] = ((u64)f2key(src[base + i]) << 32) | (u32)i;
    }
    for (int k = 2; k <= 256; k <<= 1) reg_session(e, t, k);
#pragma unroll
    for (int r = 0; r < 4; ++r) lds[4 * t + r] = e[r];
    __syncthreads();
    for (int k = 512; k <= NN; k <<= 1) {
      for (int j = k >> 1; j >= 256; j >>= 1) {
#pragma unroll
        for (int pp = 0; pp < 2; ++pp) {
          const int pw = t + pp * 1024;
          const int i = ((pw & ~(j - 1)) << 1) | (pw & (j - 1));
          const int ix = i | j;
          const bool up = ((i & k) == 0);
          const u64 a = lds[i], c = lds[ix];
          if ((a > c) == up) { lds[i] = c; lds[ix] = a; }
        }
        __syncthreads();
      }
#pragma unroll
      for (int r = 0; r < 4; ++r) e[r] = lds[4 * t + r];
      reg_session(e, t, k);
      if (k < NN) {
#pragma unroll
        for (int r = 0; r < 4; ++r) lds[4 * t + r] = e[r];
        __syncthreads();
      }
    }
    if (task == 0) {
      float kf[4], a[4], c[4];
#pragma unroll
      for (int r = 0; r < 4; ++r) {
        kf[r] = key2f((u32)(e[r] >> 32));
        f1sort[base + 4 * t + r] = kf[r];
        a[r] = expf(kf[r]);
        c[r] = expf(SLOPE * kf[r]);
      }
#pragma unroll
      for (int r = 1; r < 4; ++r) { a[r] += a[r - 1]; c[r] += c[r - 1]; }
      const float sa = a[3], sb = c[3];
      float pa = sa, pb = sb;
      for (int off = 1; off < 64; off <<= 1) {
        const float oa = __shfl_up(pa, off, 64);
        const float ob = __shfl_up(pb, off, 64);
        if (lane >= off) { pa += oa; pb += ob; }
      }
      if (lane == 63) { wsumA[wv] = pa; wsumB[wv] = pb; }
      __syncthreads();
      float wpa = 0.f, wpb = 0.f;
      for (int w2 = 0; w2 < wv; ++w2) { wpa += wsumA[w2]; wpb += wsumB[w2]; }
      const float basea = wpa + pa - sa, baseb = wpb + pb - sb;
#pragma unroll
      for (int r = 0; r < 4; ++r) {
        sc1[base + 4 * t + r] = basea + a[r];
        sc2[base + 4 * t + r] = baseb + c[r];
      }
    } else {
#pragma unroll
      for (int r = 0; r < 4; ++r) {
        f2sort[base + 4 * t + r] = key2f((u32)(e[r] >> 32));
        jidxS[base + 4 * t + r]  = (int)(e[r] & 0xffffffffu);
      }
    }
  } else {
    // ======== persistent split-bf16 MFMA GEMM (248 workers, 256 tiles) =====
    u16* axh = (u16*)smem;                 // [64][72]
    u16* axl = (u16*)(smem + 9216);
    u16* bwh = (u16*)(smem + 18432);       // [128][72]
    u16* bwl = (u16*)(smem + 36864);
    const int w = tid >> 6, lane = tid & 63;
    const int wm = w >> 2, wn = w & 3;
    const int xr = tid >> 4, xc4 = (tid & 15) * 4;   // x staging: 64r x 16 f4
    const int wcol = tid >> 3, wc = tid & 7;         // W staging: 128c x 8 b8
    bool needSync = false;

    for (int tile = bid - 8; tile < NROW / 64; tile += NWK) {
      const int row0 = tile * 64;
      f32x4 acc[2];
      acc[0] = (f32x4)0.f; acc[1] = (f32x4)0.f;
      float4 xv;
      bf16x8 whb, wlb;
      xv  = *(const float4*)(x + (size_t)(row0 + xr) * KIN + xc4);
      whb = *(const bf16x8*)(whT  + (size_t)wcol * KIN + wc * 8);
      wlb = *(const bf16x8*)(wloT + (size_t)wcol * KIN + wc * 8);

      for (int it = 0; it < 4; ++it) {
        if (it || needSync) __syncthreads();
        {
          float va[4] = {xv.x, xv.y, xv.z, xv.w};
          ushort4 hh, ll;
          const u16 h0 = f2bf(va[0]); hh.x = h0; ll.x = f2bf(va[0] - bf2f(h0));
          const u16 h1 = f2bf(va[1]); hh.y = h1; ll.y = f2bf(va[1] - bf2f(h1));
          const u16 h2 = f2bf(va[2]); hh.z = h2; ll.z = f2bf(va[2] - bf2f(h2));
          const u16 h3 = f2bf(va[3]); hh.w = h3; ll.w = f2bf(va[3] - bf2f(h3));
          *(ushort4*)(&axh[xr * 72 + xc4]) = hh;
          *(ushort4*)(&axl[xr * 72 + xc4]) = ll;
        }
        *(bf16x8*)(&bwh[wcol * 72 + wc * 8]) = whb;
        *(bf16x8*)(&bwl[wcol * 72 + wc * 8]) = wlb;
        __syncthreads();
        if (it < 3) {  // prefetch next k-chunk (overlaps MFMA)
          xv  = *(const float4*)(x + (size_t)(row0 + xr) * KIN + (it + 1) * 64 + xc4);
          whb = *(const bf16x8*)(whT  + (size_t)wcol * KIN + (it + 1) * 64 + wc * 8);
          wlb = *(const bf16x8*)(wloT + (size_t)wcol * KIN + (it + 1) * 64 + wc * 8);
        }
#pragma unroll
        for (int kk = 0; kk < 2; ++kk) {
          const int kb = kk * 32 + (lane >> 4) * 8;
          const int ar = wm * 16 + (lane & 15);
          const bf16x8 ah = *(const bf16x8*)(&axh[ar * 72 + kb]);
          const bf16x8 al = *(const bf16x8*)(&axl[ar * 72 + kb]);
#pragma unroll
          for (int n = 0; n < 2; ++n) {
            const int cidx = wn * 32 + n * 16 + (lane & 15);
            const bf16x8 bh  = *(const bf16x8*)(&bwh[cidx * 72 + kb]);
            const bf16x8 blo = *(const bf16x8*)(&bwl[cidx * 72 + kb]);
            acc[n] = __builtin_amdgcn_mfma_f32_16x16x32_bf16(ah, bh,  acc[n], 0, 0, 0);
            acc[n] = __builtin_amdgcn_mfma_f32_16x16x32_bf16(ah, blo, acc[n], 0, 0, 0);
            acc[n] = __builtin_amdgcn_mfma_f32_16x16x32_bf16(al, bh,  acc[n], 0, 0, 0);
          }
        }
      }
      needSync = true;
      // epilogue: C map col=lane&15, row=(lane>>4)*4+r
      const int rb = row0 + wm * 16 + (lane >> 4) * 4;
      const int cb = wn * 32 + (lane & 15);
#pragma unroll
      for (int n = 0; n < 2; ++n)
#pragma unroll
        for (int r = 0; r < 4; ++r)
          feats[(size_t)(rb + r) * FO + cb + n * 16] = acc[n][r];
    }
  }
}

// ---------------- Kernel 3b: alpha/beta per sorted-j, kpos/e12 per row ------
__global__ __launch_bounds__(512) void k3b_ab(const float* __restrict__ f1sort,
                                              const float* __restrict__ sc1,
                                              const float* __restrict__ sc2,
                                              const float* __restrict__ f2sort,
                                              const float* __restrict__ f1g,
                                              float* __restrict__ alphaS,
                                              float* __restrict__ betaS,
                                              int* __restrict__ kposA,
                                              float2* __restrict__ e12) {
  __shared__ float s_f1[NN];  // 16 KiB
  __shared__ float s_f2[NN];  // 16 KiB
  const int b = blockIdx.x >> 3;
  const int part = blockIdx.x & 7;
  const int base = b * NN;
  for (int i = threadIdx.x; i < NN; i += 512) {
    s_f1[i] = f1sort[base + i];
    s_f2[i] = f2sort[base + i];
  }
  __syncthreads();
  const int g = part * 512 + threadIdx.x;
  const float T1 = sc1[base + NN - 1];
  const float f1max = s_f1[NN - 1];
  {
    const float f2v = s_f2[g];
    const float m = f1max + f2v;
    const float M = (m >= 0.f) ? m : SLOPE * m;      // column max of leaky scores
    const int p = lower_bound_s(s_f1, NN, -f2v);     // first i with f1 >= -f2
    const float S1 = T1 - (p > 0 ? sc1[base + p - 1] : 0.f);
    const float S2 = (p > 0 ? sc2[base + p - 1] : 0.f);
    const float ea = expf(f2v - M);
    const float eb = expf(SLOPE * f2v - M);
    const float invD = 1.0f / (ea * S1 + eb * S2);
    alphaS[base + g] = ea * invD;
    betaS[base + g]  = eb * invD;
  }
  {
    const float f1v = f1g[base + g];
    kposA[base + g] = lower_bound_s(s_f2, NN, -f1v); // first sorted-j with f2 >= -f1
    float2 e; e.x = expf(f1v); e.y = expf(SLOPE * f1v);
    e12[base + g] = e;
  }
}

// ---------------- Kernel 4a: per-position inclusive prefixes (float2 AB) ----
__global__ __launch_bounds__(128) void k4a_pref(const float* __restrict__ feats,
                                                const float* __restrict__ alphaS,
                                                const float* __restrict__ betaS,
                                                const int* __restrict__ jidxS,
                                                float2* __restrict__ fineP,
                                                float2* __restrict__ csum) {
  const int b = blockIdx.x >> 6, cc = blockIdx.x & 63;
  const int o = threadIdx.x;
  const int base = b * NN + cc * 64;
  const float* fb = feats + (size_t)b * NN * FO;
  float accA = 0.f, accB = 0.f;
#pragma unroll 8
  for (int q = 0; q < 64; ++q) {
    const int kk = base + q;
    const int j = jidxS[kk];
    const float fv = fb[(size_t)j * FO + o];
    accA = fmaf(alphaS[kk], fv, accA);
    accB = fmaf(betaS[kk], fv, accB);
    float2 p; p.x = accA; p.y = accB;
    fineP[(size_t)kk * FO + o] = p;
  }
  float2 cts; cts.x = accA; cts.y = accB;
  csum[(size_t)(b * NCC + cc) * FO + o] = cts;     // compact chunk totals
}

// ---------------- Kernel 4c: exclusive prefix over compact chunk sums -------
__global__ __launch_bounds__(128) void k4c_coar(const float2* __restrict__ csum,
                                                float2* __restrict__ coar) {
  const int b = blockIdx.x;
  const int o = threadIdx.x;
  float runA = 0.f, runB = 0.f;
#pragma unroll
  for (int c = 0; c < NCC; ++c) {
    float2 w; w.x = runA; w.y = runB;
    coar[(size_t)(b * (NCC + 1) + c) * FO + o] = w;
    const float2 v = csum[(size_t)(b * NCC + c) * FO + o];
    runA += v.x; runB += v.y;
  }
  float2 w; w.x = runA; w.y = runB;
  coar[(size_t)(b * (NCC + 1) + NCC) * FO + o] = w;   // total
}

// ---------------- Kernel 5: streaming combine (float2 loads) ----------------
__global__ __launch_bounds__(256) void k5_out(const float2* __restrict__ fineP,
                                              const float2* __restrict__ coar,
                                              const int* __restrict__ kposA,
                                              const float2* __restrict__ e12,
                                              float* __restrict__ out) {
  const int t = threadIdx.x;
  const int row = blockIdx.x * 2 + (t >> 7);
  const int o = t & 127;
  const int b = row >> 12;  // NN = 4096
  const int kp = kposA[row];
  const float2 ev = e12[row];
  const int c = kp >> 6;          // 0..64

  float2 run = coar[(size_t)(b * (NCC + 1) + c) * FO + o];
  const float2 tot = coar[(size_t)(b * (NCC + 1) + NCC) * FO + o];
  if (kp & 63) {
    const float2 f = fineP[(size_t)(b * NN + kp - 1) * FO + o];
    run.x += f.x; run.y += f.y;
  }
  out[(size_t)row * FO + o] = fmaf(ev.x, tot.x - run.x, ev.y * run.y);
}

extern "C" void kernel_launch(void* const* d_in, const int* in_sizes, int n_in,
                              void* d_out, int out_size, void* d_ws, size_t ws_size,
                              hipStream_t stream) {
  const float* x  = (const float*)d_in[0];
  const float* W  = (const float*)d_in[1];
  const float* wl = (const float*)d_in[2];
  const float* bl = (const float*)d_in[3];
  const float* wr = (const float*)d_in[4];
  const float* br = (const float*)d_in[5];
  float* out = (float*)d_out;

  float* ws = (float*)d_ws;
  float* feats    = ws; ws += NROW * FO;
  float2* fineP   = (float2*)ws; ws += NROW * FO * 2;
  float* f1g      = ws; ws += NROW;
  float* f2g      = ws; ws += NROW;
  float* f1sort   = ws; ws += NROW;
  float* f2sort   = ws; ws += NROW;
  float* sc1      = ws; ws += NROW;
  float* sc2      = ws; ws += NROW;
  float* alphaS   = ws; ws += NROW;
  float* betaS    = ws; ws += NROW;
  float2* e12     = (float2*)ws; ws += NROW * 2;
  int* jidxS      = (int*)ws; ws += NROW;
  int* kposA      = (int*)ws; ws += NROW;
  float2* coar    = (float2*)ws; ws += NB * (NCC + 1) * FO * 2;
  float2* csum    = (float2*)ws; ws += NB * NCC * FO * 2;
  u16* whT  = (u16*)ws; ws += FO * KIN / 2;     // bf16 [128 col][256 k]
  u16* wloT = (u16*)ws; ws += FO * KIN / 2;
  (void)in_sizes; (void)n_in; (void)out_size; (void)ws_size;

  hipLaunchKernelGGL(k0_prep,  dim3(NROW / 64), dim3(256),  0, stream,
                     x, W, wl, bl, wr, br, whT, wloT, f1g, f2g);
  hipLaunchKernelGGL(kB_main,  dim3(256),       dim3(1024), 0, stream,
                     x, whT, wloT, f1g, f2g, feats,
                     f1sort, sc1, sc2, f2sort, jidxS);
  hipLaunchKernelGGL(k3b_ab,   dim3(NB * 8),    dim3(512),  0, stream,
                     f1sort, sc1, sc2, f2sort, f1g, alphaS, betaS, kposA, e12);
  hipLaunchKernelGGL(k4a_pref, dim3(NB * NCC),  dim3(128),  0, stream,
                     feats, alphaS, betaS, jidxS, fineP, csum);
  hipLaunchKernelGGL(k4c_coar, dim3(NB),        dim3(128),  0, stream,
                     csum, coar);
  hipLaunchKernelGGL(k5_out,   dim3(NROW / 2),  dim3(256),  0, stream,
                     fineP, coar, kposA, e12, out);
}

// Round 19
// 65.450 us; speedup vs baseline: 1.0569x; 1.0373x over previous
//
#include <hip/hip_runtime.h>

using u16 = unsigned short;
using u32 = unsigned int;
using u64 = unsigned long long;

typedef short bf16x8 __attribute__((ext_vector_type(8)));
typedef float f32x4 __attribute__((ext_vector_type(4)));

static constexpr int NB  = 4;     // batch
static constexpr int NN  = 4096;  // nodes
static constexpr int KIN = 256;   // in features
static constexpr int FO  = 128;   // out features
static constexpr int NROW = NB * NN;  // 16384 total rows
static constexpr int NCC = 64;    // coarse chunks per batch (64 positions each)
static constexpr int NWK = 248;   // persistent GEMM workers in kB
static constexpr float SLOPE = 0.01f;

// ---- bf16 helpers (RNE, no NaN inputs) ----
__device__ __forceinline__ u16 f2bf(float f) {
  const u32 u = __float_as_uint(f);
  return (u16)((u + 0x7fffu + ((u >> 16) & 1u)) >> 16);
}
__device__ __forceinline__ float bf2f(u16 h) {
  return __uint_as_float(((u32)h) << 16);
}
__device__ __forceinline__ float dot4(const float4& a, const float4& b) {
  return a.x * b.x + a.y * b.y + a.z * b.z + a.w * b.w;
}

// monotone bijection f32 -> orderable u32 (no NaNs present)
__device__ __forceinline__ u32 f2key(float f) {
  const u32 b = __float_as_uint(f);
  return (b & 0x80000000u) ? ~b : (b | 0x80000000u);
}
__device__ __forceinline__ float key2f(u32 u) {
  const u32 b = (u & 0x80000000u) ? (u ^ 0x80000000u) : ~u;
  return __uint_as_float(b);
}

__device__ __forceinline__ u64 shfl_xor64(u64 v, int m) {
  const u32 lo = __shfl_xor((u32)(v & 0xffffffffu), m, 64);
  const u32 hi = __shfl_xor((u32)(v >> 32), m, 64);
  return ((u64)hi << 32) | (u64)lo;
}
__device__ __forceinline__ void cswap(u64& a, u64& b, bool up) {
  if ((a > b) == up) { const u64 tmp = a; a = b; b = tmp; }
}

// bitonic rounds j = min(k/2,128)..1 for phase k, data in registers.
__device__ __forceinline__ void reg_session(u64 e[4], int t, int k) {
  const int jstart = (k > 256) ? 128 : (k >> 1);
  for (int j = jstart; j >= 4; j >>= 1) {
    const int J = j >> 2;
    const bool up   = ((t & (k >> 2)) == 0);
    const bool lowr = ((t & J) == 0);
#pragma unroll
    for (int r = 0; r < 4; ++r) {
      const u64 o = shfl_xor64(e[r], J);
      const bool less = e[r] < o;              // keys unique (idx tie-break)
      e[r] = ((lowr == up) == less) ? e[r] : o;
    }
  }
  if (k >= 4) {
    const bool up = ((t & (k >> 2)) == 0);
    cswap(e[0], e[2], up); cswap(e[1], e[3], up);
  }
  {
    const bool up0 = (((4 * t)     & k) == 0);
    const bool up1 = (((4 * t + 2) & k) == 0);
    cswap(e[0], e[1], up0); cswap(e[2], e[3], up1);
  }
}

__device__ __forceinline__ int lower_bound_g(const float* __restrict__ a, int n, float t) {
  int lo = 0, hi = n;
  while (lo < hi) {
    const int mid = (lo + hi) >> 1;
    if (a[mid] < t) lo = mid + 1; else hi = mid;
  }
  return lo;
}

// ---------------- Kernel 0: W split + exact f1/f2 (pre-GEMM) ---------------
// grid 256 x 256. Every block: u_l/u_r in LDS (thread t = k-row), then
// f1/f2 for 64 rows (wave per 16 rows, lane-parallel dot + shfl reduce).
// Blocks 0-63 additionally write the Wh/Wl bf16 transposed split.
__global__ __launch_bounds__(256) void k0_prep(const float* __restrict__ x,
                                               const float* __restrict__ W,
                                               const float* __restrict__ wl,
                                               const float* __restrict__ blp,
                                               const float* __restrict__ wr,
                                               const float* __restrict__ brp,
                                               u16* __restrict__ whT,
                                               u16* __restrict__ wloT,
                                               float* __restrict__ f1g,
                                               float* __restrict__ f2g) {
  __shared__ float uls[KIN];
  __shared__ float urs[KIN];
  const int t = threadIdx.x;
  const int bid = blockIdx.x;

  if (bid < 64) {  // W hi/lo split transpose
#pragma unroll
    for (int e = 0; e < 2; ++e) {
      const int idx = bid * 512 + t + e * 256;  // 0..32767
      const int col = idx >> 8, k = idx & 255;
      const float v = W[k * FO + col];
      const u16 h = f2bf(v);
      whT[col * KIN + k]  = h;
      wloT[col * KIN + k] = f2bf(v - bf2f(h));
    }
  }
  // u_l[k]/u_r[k] for k = t (exact f32 serial dot; W L2-hot)
  {
    const float* Wr = W + (size_t)t * FO;
    float s1 = 0.f, s2 = 0.f;
#pragma unroll 8
    for (int c = 0; c < FO; ++c) {
      const float wv = Wr[c];
      s1 = fmaf(wv, wl[c], s1);
      s2 = fmaf(wv, wr[c], s2);
    }
    uls[t] = s1; urs[t] = s2;
  }
  __syncthreads();
  // f1/f2: wave wv handles 16 rows serially; 64 lanes x float4 covers a row
  const int wv = t >> 6, lane = t & 63;
  const int row0 = bid * 64 + wv * 16;
  const float4 ul = *(const float4*)(&uls[lane * 4]);
  const float4 ur = *(const float4*)(&urs[lane * 4]);
  const float blv = blp[0], brv = brp[0];
  for (int r = 0; r < 16; ++r) {
    const int row = row0 + r;
    const float4 xv = *(const float4*)(x + (size_t)row * KIN + lane * 4);
    float d1 = dot4(xv, ul);
    float d2 = dot4(xv, ur);
#pragma unroll
    for (int off = 1; off < 64; off <<= 1) {
      d1 += __shfl_xor(d1, off, 64);
      d2 += __shfl_xor(d2, off, 64);
    }
    if (lane == 0) { f1g[row] = d1 + blv; f2g[row] = d2 + brv; }
  }
}

// ---------------- Kernel B: sort (blocks 0-7) || persistent MFMA GEMM ------
// grid 256 x 1024. Sort path: R8 k3a verbatim. GEMM path: 248 workers loop
// over 256 tiles (BM=64, 16 waves 4x4, wave-tile 16x32, split-bf16 MFMA).
__global__ __launch_bounds__(1024, 1) void kB_main(const float* __restrict__ x,
                                                   const u16* __restrict__ whT,
                                                   const u16* __restrict__ wloT,
                                                   const float* __restrict__ f1g,
                                                   const float* __restrict__ f2g,
                                                   float* __restrict__ feats,
                                                   float* __restrict__ f1sort,
                                                   float* __restrict__ sc1,
                                                   float* __restrict__ sc2,
                                                   float* __restrict__ f2sort,
                                                   int* __restrict__ jidxS) {
  __shared__ __align__(16) unsigned char smem[55296];
  const int tid = threadIdx.x;
  const int bid = blockIdx.x;

  if (bid < 8) {
    // ======== hierarchical bitonic sort + exp scans (R8 k3a) ========
    u64* lds = (u64*)smem;                  // [4096] = 32 KiB
    float* wsumA = (float*)(smem + 32768);  // [16]
    float* wsumB = (float*)(smem + 32832);  // [16]
    const int t = tid;
    const int lane = t & 63, wv = t >> 6;
    const int b = bid & 3;
    const int task = bid >> 2;
    const int base = b * NN;
    const float* __restrict__ src = task ? f2g : f1g;

    u64 e[4];
#pragma unroll
    for (int r = 0; r < 4; ++r) {
      const int i = 4 * t + r;
      e[r] = ((u64)f2key(src[base + i]) << 32) | (u32)i;
    }
    for (int k = 2; k <= 256; k <<= 1) reg_session(e, t, k);
#pragma unroll
    for (int r = 0; r < 4; ++r) lds[4 * t + r] = e[r];
    __syncthreads();
    for (int k = 512; k <= NN; k <<= 1) {
      for (int j = k >> 1; j >= 256; j >>= 1) {
#pragma unroll
        for (int pp = 0; pp < 2; ++pp) {
          const int pw = t + pp * 1024;
          const int i = ((pw & ~(j - 1)) << 1) | (pw & (j - 1));
          const int ix = i | j;
          const bool up = ((i & k) == 0);
          const u64 a = lds[i], c = lds[ix];
          if ((a > c) == up) { lds[i] = c; lds[ix] = a; }
        }
        __syncthreads();
      }
#pragma unroll
      for (int r = 0; r < 4; ++r) e[r] = lds[4 * t + r];
      reg_session(e, t, k);
      if (k < NN) {
#pragma unroll
        for (int r = 0; r < 4; ++r) lds[4 * t + r] = e[r];
        __syncthreads();
      }
    }
    if (task == 0) {
      float kf[4], a[4], c[4];
#pragma unroll
      for (int r = 0; r < 4; ++r) {
        kf[r] = key2f((u32)(e[r] >> 32));
        f1sort[base + 4 * t + r] = kf[r];
        a[r] = expf(kf[r]);
        c[r] = expf(SLOPE * kf[r]);
      }
#pragma unroll
      for (int r = 1; r < 4; ++r) { a[r] += a[r - 1]; c[r] += c[r - 1]; }
      const float sa = a[3], sb = c[3];
      float pa = sa, pb = sb;
      for (int off = 1; off < 64; off <<= 1) {
        const float oa = __shfl_up(pa, off, 64);
        const float ob = __shfl_up(pb, off, 64);
        if (lane >= off) { pa += oa; pb += ob; }
      }
      if (lane == 63) { wsumA[wv] = pa; wsumB[wv] = pb; }
      __syncthreads();
      float wpa = 0.f, wpb = 0.f;
      for (int w2 = 0; w2 < wv; ++w2) { wpa += wsumA[w2]; wpb += wsumB[w2]; }
      const float basea = wpa + pa - sa, baseb = wpb + pb - sb;
#pragma unroll
      for (int r = 0; r < 4; ++r) {
        sc1[base + 4 * t + r] = basea + a[r];
        sc2[base + 4 * t + r] = baseb + c[r];
      }
    } else {
#pragma unroll
      for (int r = 0; r < 4; ++r) {
        f2sort[base + 4 * t + r] = key2f((u32)(e[r] >> 32));
        jidxS[base + 4 * t + r]  = (int)(e[r] & 0xffffffffu);
      }
    }
  } else {
    // ======== persistent split-bf16 MFMA GEMM (248 workers, 256 tiles) =====
    u16* axh = (u16*)smem;                 // [64][72]
    u16* axl = (u16*)(smem + 9216);
    u16* bwh = (u16*)(smem + 18432);       // [128][72]
    u16* bwl = (u16*)(smem + 36864);
    const int w = tid >> 6, lane = tid & 63;
    const int wm = w >> 2, wn = w & 3;
    const int xr = tid >> 4, xc4 = (tid & 15) * 4;   // x staging: 64r x 16 f4
    const int wcol = tid >> 3, wc = tid & 7;         // W staging: 128c x 8 b8
    bool needSync = false;

    for (int tile = bid - 8; tile < NROW / 64; tile += NWK) {
      const int row0 = tile * 64;
      f32x4 acc[2];
      acc[0] = (f32x4)0.f; acc[1] = (f32x4)0.f;
      float4 xv;
      bf16x8 whb, wlb;
      xv  = *(const float4*)(x + (size_t)(row0 + xr) * KIN + xc4);
      whb = *(const bf16x8*)(whT  + (size_t)wcol * KIN + wc * 8);
      wlb = *(const bf16x8*)(wloT + (size_t)wcol * KIN + wc * 8);

      for (int it = 0; it < 4; ++it) {
        if (it || needSync) __syncthreads();
        {
          float va[4] = {xv.x, xv.y, xv.z, xv.w};
          ushort4 hh, ll;
          const u16 h0 = f2bf(va[0]); hh.x = h0; ll.x = f2bf(va[0] - bf2f(h0));
          const u16 h1 = f2bf(va[1]); hh.y = h1; ll.y = f2bf(va[1] - bf2f(h1));
          const u16 h2 = f2bf(va[2]); hh.z = h2; ll.z = f2bf(va[2] - bf2f(h2));
          const u16 h3 = f2bf(va[3]); hh.w = h3; ll.w = f2bf(va[3] - bf2f(h3));
          *(ushort4*)(&axh[xr * 72 + xc4]) = hh;
          *(ushort4*)(&axl[xr * 72 + xc4]) = ll;
        }
        *(bf16x8*)(&bwh[wcol * 72 + wc * 8]) = whb;
        *(bf16x8*)(&bwl[wcol * 72 + wc * 8]) = wlb;
        __syncthreads();
        if (it < 3) {  // prefetch next k-chunk (overlaps MFMA)
          xv  = *(const float4*)(x + (size_t)(row0 + xr) * KIN + (it + 1) * 64 + xc4);
          whb = *(const bf16x8*)(whT  + (size_t)wcol * KIN + (it + 1) * 64 + wc * 8);
          wlb = *(const bf16x8*)(wloT + (size_t)wcol * KIN + (it + 1) * 64 + wc * 8);
        }
#pragma unroll
        for (int kk = 0; kk < 2; ++kk) {
          const int kb = kk * 32 + (lane >> 4) * 8;
          const int ar = wm * 16 + (lane & 15);
          const bf16x8 ah = *(const bf16x8*)(&axh[ar * 72 + kb]);
          const bf16x8 al = *(const bf16x8*)(&axl[ar * 72 + kb]);
#pragma unroll
          for (int n = 0; n < 2; ++n) {
            const int cidx = wn * 32 + n * 16 + (lane & 15);
            const bf16x8 bh  = *(const bf16x8*)(&bwh[cidx * 72 + kb]);
            const bf16x8 blo = *(const bf16x8*)(&bwl[cidx * 72 + kb]);
            acc[n] = __builtin_amdgcn_mfma_f32_16x16x32_bf16(ah, bh,  acc[n], 0, 0, 0);
            acc[n] = __builtin_amdgcn_mfma_f32_16x16x32_bf16(ah, blo, acc[n], 0, 0, 0);
            acc[n] = __builtin_amdgcn_mfma_f32_16x16x32_bf16(al, bh,  acc[n], 0, 0, 0);
          }
        }
      }
      needSync = true;
      // epilogue: C map col=lane&15, row=(lane>>4)*4+r
      const int rb = row0 + wm * 16 + (lane >> 4) * 4;
      const int cb = wn * 32 + (lane & 15);
#pragma unroll
      for (int n = 0; n < 2; ++n)
#pragma unroll
        for (int r = 0; r < 4; ++r)
          feats[(size_t)(rb + r) * FO + cb + n * 16] = acc[n][r];
    }
  }
}

// ---------------- Kernel 4a: alpha/beta + kpos/e12 + prefixes (fence-free) --
// grid NB*NCC x 128. Waves 0/1 compute the chunk's 32+32 alpha/beta and the
// chunk rows' kpos/e12 via global binary searches (f1sort/f2sort L2-hot),
// then all 128 threads do the gather walk. Formulas identical to old k3b.
__global__ __launch_bounds__(128) void k4a_pref(const float* __restrict__ feats,
                                                const float* __restrict__ f1sort,
                                                const float* __restrict__ sc1,
                                                const float* __restrict__ sc2,
                                                const float* __restrict__ f2sort,
                                                const float* __restrict__ f1g,
                                                const int* __restrict__ jidxS,
                                                float2* __restrict__ fineP,
                                                float2* __restrict__ csum,
                                                int* __restrict__ kposA,
                                                float2* __restrict__ e12) {
  __shared__ float sal[64], sbe[64];
  const int b = blockIdx.x >> 6, cc = blockIdx.x & 63;
  const int tid = threadIdx.x;
  const int bb = b * NN;
  const int base = bb + cc * 64;

  if (tid < 64) {
    // alpha/beta for sorted-j position pos = cc*64 + tid
    const int pos = cc * 64 + tid;
    const float T1 = sc1[bb + NN - 1];
    const float f1max = f1sort[bb + NN - 1];
    const float f2v = f2sort[bb + pos];
    const float m = f1max + f2v;
    const float M = (m >= 0.f) ? m : SLOPE * m;          // column max of leaky scores
    const int pp = lower_bound_g(f1sort + bb, NN, -f2v); // first i with f1 >= -f2
    const float S1 = T1 - (pp > 0 ? sc1[bb + pp - 1] : 0.f);
    const float S2 = (pp > 0 ? sc2[bb + pp - 1] : 0.f);
    const float ea = expf(f2v - M);
    const float eb = expf(SLOPE * f2v - M);
    const float invD = 1.0f / (ea * S1 + eb * S2);
    sal[tid] = ea * invD;
    sbe[tid] = eb * invD;
  } else {
    // kpos/e12 for row cc*64 + (tid-64)
    const int row = cc * 64 + (tid - 64);
    const float f1v = f1g[bb + row];
    kposA[bb + row] = lower_bound_g(f2sort + bb, NN, -f1v);
    float2 e; e.x = expf(f1v); e.y = expf(SLOPE * f1v);
    e12[bb + row] = e;
  }
  __syncthreads();

  // gather walk: per-position inclusive prefixes + compact chunk total
  const int o = tid;
  const float* fb = feats + (size_t)b * NN * FO;
  float accA = 0.f, accB = 0.f;
#pragma unroll 8
  for (int q = 0; q < 64; ++q) {
    const int kk = base + q;
    const int j = jidxS[kk];
    const float fv = fb[(size_t)j * FO + o];
    accA = fmaf(sal[q], fv, accA);
    accB = fmaf(sbe[q], fv, accB);
    float2 p; p.x = accA; p.y = accB;
    fineP[(size_t)kk * FO + o] = p;
  }
  float2 cts; cts.x = accA; cts.y = accB;
  csum[(size_t)(b * NCC + cc) * FO + o] = cts;
}

// ---------------- Kernel 4c: exclusive prefix over compact chunk sums -------
__global__ __launch_bounds__(128) void k4c_coar(const float2* __restrict__ csum,
                                                float2* __restrict__ coar) {
  const int b = blockIdx.x;
  const int o = threadIdx.x;
  float runA = 0.f, runB = 0.f;
#pragma unroll
  for (int c = 0; c < NCC; ++c) {
    float2 w; w.x = runA; w.y = runB;
    coar[(size_t)(b * (NCC + 1) + c) * FO + o] = w;
    const float2 v = csum[(size_t)(b * NCC + c) * FO + o];
    runA += v.x; runB += v.y;
  }
  float2 w; w.x = runA; w.y = runB;
  coar[(size_t)(b * (NCC + 1) + NCC) * FO + o] = w;   // total
}

// ---------------- Kernel 5: streaming combine (float2 loads) ----------------
__global__ __launch_bounds__(256) void k5_out(const float2* __restrict__ fineP,
                                              const float2* __restrict__ coar,
                                              const int* __restrict__ kposA,
                                              const float2* __restrict__ e12,
                                              float* __restrict__ out) {
  const int t = threadIdx.x;
  const int row = blockIdx.x * 2 + (t >> 7);
  const int o = t & 127;
  const int b = row >> 12;  // NN = 4096
  const int kp = kposA[row];
  const float2 ev = e12[row];
  const int c = kp >> 6;          // 0..64

  float2 run = coar[(size_t)(b * (NCC + 1) + c) * FO + o];
  const float2 tot = coar[(size_t)(b * (NCC + 1) + NCC) * FO + o];
  if (kp & 63) {
    const float2 f = fineP[(size_t)(b * NN + kp - 1) * FO + o];
    run.x += f.x; run.y += f.y;
  }
  out[(size_t)row * FO + o] = fmaf(ev.x, tot.x - run.x, ev.y * run.y);
}

extern "C" void kernel_launch(void* const* d_in, const int* in_sizes, int n_in,
                              void* d_out, int out_size, void* d_ws, size_t ws_size,
                              hipStream_t stream) {
  const float* x  = (const float*)d_in[0];
  const float* W  = (const float*)d_in[1];
  const float* wl = (const float*)d_in[2];
  const float* bl = (const float*)d_in[3];
  const float* wr = (const float*)d_in[4];
  const float* br = (const float*)d_in[5];
  float* out = (float*)d_out;

  float* ws = (float*)d_ws;
  float* feats    = ws; ws += NROW * FO;
  float2* fineP   = (float2*)ws; ws += NROW * FO * 2;
  float* f1g      = ws; ws += NROW;
  float* f2g      = ws; ws += NROW;
  float* f1sort   = ws; ws += NROW;
  float* f2sort   = ws; ws += NROW;
  float* sc1      = ws; ws += NROW;
  float* sc2      = ws; ws += NROW;
  float2* e12     = (float2*)ws; ws += NROW * 2;
  int* jidxS      = (int*)ws; ws += NROW;
  int* kposA      = (int*)ws; ws += NROW;
  float2* coar    = (float2*)ws; ws += NB * (NCC + 1) * FO * 2;
  float2* csum    = (float2*)ws; ws += NB * NCC * FO * 2;
  u16* whT  = (u16*)ws; ws += FO * KIN / 2;     // bf16 [128 col][256 k]
  u16* wloT = (u16*)ws; ws += FO * KIN / 2;
  (void)in_sizes; (void)n_in; (void)out_size; (void)ws_size;

  hipLaunchKernelGGL(k0_prep,  dim3(NROW / 64), dim3(256),  0, stream,
                     x, W, wl, bl, wr, br, whT, wloT, f1g, f2g);
  hipLaunchKernelGGL(kB_main,  dim3(256),       dim3(1024), 0, stream,
                     x, whT, wloT, f1g, f2g, feats,
                     f1sort, sc1, sc2, f2sort, jidxS);
  hipLaunchKernelGGL(k4a_pref, dim3(NB * NCC),  dim3(128),  0, stream,
                     feats, f1sort, sc1, sc2, f2sort, f1g, jidxS,
                     fineP, csum, kposA, e12);
  hipLaunchKernelGGL(k4c_coar, dim3(NB),        dim3(128),  0, stream,
                     csum, coar);
  hipLaunchKernelGGL(k5_out,   dim3(NROW / 2),  dim3(256),  0, stream,
                     fineP, coar, kposA, e12, out);
}

// Round 20
// 63.865 us; speedup vs baseline: 1.0831x; 1.0248x over previous
//
#include <hip/hip_runtime.h>

using u16 = unsigned short;
using u32 = unsigned int;
using u64 = unsigned long long;

typedef short bf16x8 __attribute__((ext_vector_type(8)));
typedef float f32x4 __attribute__((ext_vector_type(4)));

static constexpr int NB  = 4;     // batch
static constexpr int NN  = 4096;  // nodes
static constexpr int KIN = 256;   // in features
static constexpr int FO  = 128;   // out features
static constexpr int NROW = NB * NN;  // 16384 total rows
static constexpr int NCC = 64;    // coarse chunks per batch (64 positions each)
static constexpr int NWK = 248;   // persistent GEMM workers in kB
static constexpr float SLOPE = 0.01f;

// ---- bf16 helpers (RNE, no NaN inputs) ----
__device__ __forceinline__ u16 f2bf(float f) {
  const u32 u = __float_as_uint(f);
  return (u16)((u + 0x7fffu + ((u >> 16) & 1u)) >> 16);
}
__device__ __forceinline__ float bf2f(u16 h) {
  return __uint_as_float(((u32)h) << 16);
}
__device__ __forceinline__ float dot4(const float4& a, const float4& b) {
  return a.x * b.x + a.y * b.y + a.z * b.z + a.w * b.w;
}

// monotone bijection f32 -> orderable u32 (no NaNs present)
__device__ __forceinline__ u32 f2key(float f) {
  const u32 b = __float_as_uint(f);
  return (b & 0x80000000u) ? ~b : (b | 0x80000000u);
}
__device__ __forceinline__ float key2f(u32 u) {
  const u32 b = (u & 0x80000000u) ? (u ^ 0x80000000u) : ~u;
  return __uint_as_float(b);
}

__device__ __forceinline__ u64 shfl_xor64(u64 v, int m) {
  const u32 lo = __shfl_xor((u32)(v & 0xffffffffu), m, 64);
  const u32 hi = __shfl_xor((u32)(v >> 32), m, 64);
  return ((u64)hi << 32) | (u64)lo;
}
__device__ __forceinline__ void cswap(u64& a, u64& b, bool up) {
  if ((a > b) == up) { const u64 tmp = a; a = b; b = tmp; }
}

// bitonic rounds j = min(k/2,128)..1 for phase k, data in registers.
__device__ __forceinline__ void reg_session(u64 e[4], int t, int k) {
  const int jstart = (k > 256) ? 128 : (k >> 1);
  for (int j = jstart; j >= 4; j >>= 1) {
    const int J = j >> 2;
    const bool up   = ((t & (k >> 2)) == 0);
    const bool lowr = ((t & J) == 0);
#pragma unroll
    for (int r = 0; r < 4; ++r) {
      const u64 o = shfl_xor64(e[r], J);
      const bool less = e[r] < o;              // keys unique (idx tie-break)
      e[r] = ((lowr == up) == less) ? e[r] : o;
    }
  }
  if (k >= 4) {
    const bool up = ((t & (k >> 2)) == 0);
    cswap(e[0], e[2], up); cswap(e[1], e[3], up);
  }
  {
    const bool up0 = (((4 * t)     & k) == 0);
    const bool up1 = (((4 * t + 2) & k) == 0);
    cswap(e[0], e[1], up0); cswap(e[2], e[3], up1);
  }
}

__device__ __forceinline__ int lower_bound_g(const float* __restrict__ a, int n, float t) {
  int lo = 0, hi = n;
  while (lo < hi) {
    const int mid = (lo + hi) >> 1;
    if (a[mid] < t) lo = mid + 1; else hi = mid;
  }
  return lo;
}

// ---------------- Kernel 0: W split + exact f1/f2 (pre-GEMM) ---------------
// grid 256 x 256. Every block: u_l/u_r in LDS (thread t = k-row), then
// f1/f2 for 64 rows (wave per 16 rows, lane-parallel dot + shfl reduce).
// Blocks 0-63 additionally write the Wh/Wl bf16 transposed split.
__global__ __launch_bounds__(256) void k0_prep(const float* __restrict__ x,
                                               const float* __restrict__ W,
                                               const float* __restrict__ wl,
                                               const float* __restrict__ blp,
                                               const float* __restrict__ wr,
                                               const float* __restrict__ brp,
                                               u16* __restrict__ whT,
                                               u16* __restrict__ wloT,
                                               float* __restrict__ f1g,
                                               float* __restrict__ f2g) {
  __shared__ float uls[KIN];
  __shared__ float urs[KIN];
  const int t = threadIdx.x;
  const int bid = blockIdx.x;

  if (bid < 64) {  // W hi/lo split transpose
#pragma unroll
    for (int e = 0; e < 2; ++e) {
      const int idx = bid * 512 + t + e * 256;  // 0..32767
      const int col = idx >> 8, k = idx & 255;
      const float v = W[k * FO + col];
      const u16 h = f2bf(v);
      whT[col * KIN + k]  = h;
      wloT[col * KIN + k] = f2bf(v - bf2f(h));
    }
  }
  // u_l[k]/u_r[k] for k = t (exact f32 serial dot; W L2-hot)
  {
    const float* Wr = W + (size_t)t * FO;
    float s1 = 0.f, s2 = 0.f;
#pragma unroll 8
    for (int c = 0; c < FO; ++c) {
      const float wv = Wr[c];
      s1 = fmaf(wv, wl[c], s1);
      s2 = fmaf(wv, wr[c], s2);
    }
    uls[t] = s1; urs[t] = s2;
  }
  __syncthreads();
  // f1/f2: wave wv handles 16 rows serially; 64 lanes x float4 covers a row
  const int wv = t >> 6, lane = t & 63;
  const int row0 = bid * 64 + wv * 16;
  const float4 ul = *(const float4*)(&uls[lane * 4]);
  const float4 ur = *(const float4*)(&urs[lane * 4]);
  const float blv = blp[0], brv = brp[0];
  for (int r = 0; r < 16; ++r) {
    const int row = row0 + r;
    const float4 xv = *(const float4*)(x + (size_t)row * KIN + lane * 4);
    float d1 = dot4(xv, ul);
    float d2 = dot4(xv, ur);
#pragma unroll
    for (int off = 1; off < 64; off <<= 1) {
      d1 += __shfl_xor(d1, off, 64);
      d2 += __shfl_xor(d2, off, 64);
    }
    if (lane == 0) { f1g[row] = d1 + blv; f2g[row] = d2 + brv; }
  }
}

// ---------------- Kernel B: sort (blocks 0-7) || persistent MFMA GEMM ------
// grid 256 x 1024. Sort path: R8 k3a verbatim. GEMM path: 248 workers loop
// over 256 tiles (BM=64, 16 waves 4x4, wave-tile 16x32, split-bf16 MFMA).
__global__ __launch_bounds__(1024, 1) void kB_main(const float* __restrict__ x,
                                                   const u16* __restrict__ whT,
                                                   const u16* __restrict__ wloT,
                                                   const float* __restrict__ f1g,
                                                   const float* __restrict__ f2g,
                                                   float* __restrict__ feats,
                                                   float* __restrict__ f1sort,
                                                   float* __restrict__ sc1,
                                                   float* __restrict__ sc2,
                                                   float* __restrict__ f2sort,
                                                   int* __restrict__ jidxS) {
  __shared__ __align__(16) unsigned char smem[55296];
  const int tid = threadIdx.x;
  const int bid = blockIdx.x;

  if (bid < 8) {
    // ======== hierarchical bitonic sort + exp scans (R8 k3a) ========
    u64* lds = (u64*)smem;                  // [4096] = 32 KiB
    float* wsumA = (float*)(smem + 32768);  // [16]
    float* wsumB = (float*)(smem + 32832);  // [16]
    const int t = tid;
    const int lane = t & 63, wv = t >> 6;
    const int b = bid & 3;
    const int task = bid >> 2;
    const int base = b * NN;
    const float* __restrict__ src = task ? f2g : f1g;

    u64 e[4];
#pragma unroll
    for (int r = 0; r < 4; ++r) {
      const int i = 4 * t + r;
      e[r] = ((u64)f2key(src[base + i]) << 32) | (u32)i;
    }
    for (int k = 2; k <= 256; k <<= 1) reg_session(e, t, k);
#pragma unroll
    for (int r = 0; r < 4; ++r) lds[4 * t + r] = e[r];
    __syncthreads();
    for (int k = 512; k <= NN; k <<= 1) {
      for (int j = k >> 1; j >= 256; j >>= 1) {
#pragma unroll
        for (int pp = 0; pp < 2; ++pp) {
          const int pw = t + pp * 1024;
          const int i = ((pw & ~(j - 1)) << 1) | (pw & (j - 1));
          const int ix = i | j;
          const bool up = ((i & k) == 0);
          const u64 a = lds[i], c = lds[ix];
          if ((a > c) == up) { lds[i] = c; lds[ix] = a; }
        }
        __syncthreads();
      }
#pragma unroll
      for (int r = 0; r < 4; ++r) e[r] = lds[4 * t + r];
      reg_session(e, t, k);
      if (k < NN) {
#pragma unroll
        for (int r = 0; r < 4; ++r) lds[4 * t + r] = e[r];
        __syncthreads();
      }
    }
    if (task == 0) {
      float kf[4], a[4], c[4];
#pragma unroll
      for (int r = 0; r < 4; ++r) {
        kf[r] = key2f((u32)(e[r] >> 32));
        f1sort[base + 4 * t + r] = kf[r];
        a[r] = expf(kf[r]);
        c[r] = expf(SLOPE * kf[r]);
      }
#pragma unroll
      for (int r = 1; r < 4; ++r) { a[r] += a[r - 1]; c[r] += c[r - 1]; }
      const float sa = a[3], sb = c[3];
      float pa = sa, pb = sb;
      for (int off = 1; off < 64; off <<= 1) {
        const float oa = __shfl_up(pa, off, 64);
        const float ob = __shfl_up(pb, off, 64);
        if (lane >= off) { pa += oa; pb += ob; }
      }
      if (lane == 63) { wsumA[wv] = pa; wsumB[wv] = pb; }
      __syncthreads();
      float wpa = 0.f, wpb = 0.f;
      for (int w2 = 0; w2 < wv; ++w2) { wpa += wsumA[w2]; wpb += wsumB[w2]; }
      const float basea = wpa + pa - sa, baseb = wpb + pb - sb;
#pragma unroll
      for (int r = 0; r < 4; ++r) {
        sc1[base + 4 * t + r] = basea + a[r];
        sc2[base + 4 * t + r] = baseb + c[r];
      }
    } else {
#pragma unroll
      for (int r = 0; r < 4; ++r) {
        f2sort[base + 4 * t + r] = key2f((u32)(e[r] >> 32));
        jidxS[base + 4 * t + r]  = (int)(e[r] & 0xffffffffu);
      }
    }
  } else {
    // ======== persistent split-bf16 MFMA GEMM (248 workers, 256 tiles) =====
    u16* axh = (u16*)smem;                 // [64][72]
    u16* axl = (u16*)(smem + 9216);
    u16* bwh = (u16*)(smem + 18432);       // [128][72]
    u16* bwl = (u16*)(smem + 36864);
    const int w = tid >> 6, lane = tid & 63;
    const int wm = w >> 2, wn = w & 3;
    const int xr = tid >> 4, xc4 = (tid & 15) * 4;   // x staging: 64r x 16 f4
    const int wcol = tid >> 3, wc = tid & 7;         // W staging: 128c x 8 b8
    bool needSync = false;

    for (int tile = bid - 8; tile < NROW / 64; tile += NWK) {
      const int row0 = tile * 64;
      f32x4 acc[2];
      acc[0] = (f32x4)0.f; acc[1] = (f32x4)0.f;
      float4 xv;
      bf16x8 whb, wlb;
      xv  = *(const float4*)(x + (size_t)(row0 + xr) * KIN + xc4);
      whb = *(const bf16x8*)(whT  + (size_t)wcol * KIN + wc * 8);
      wlb = *(const bf16x8*)(wloT + (size_t)wcol * KIN + wc * 8);

      for (int it = 0; it < 4; ++it) {
        if (it || needSync) __syncthreads();
        {
          float va[4] = {xv.x, xv.y, xv.z, xv.w};
          ushort4 hh, ll;
          const u16 h0 = f2bf(va[0]); hh.x = h0; ll.x = f2bf(va[0] - bf2f(h0));
          const u16 h1 = f2bf(va[1]); hh.y = h1; ll.y = f2bf(va[1] - bf2f(h1));
          const u16 h2 = f2bf(va[2]); hh.z = h2; ll.z = f2bf(va[2] - bf2f(h2));
          const u16 h3 = f2bf(va[3]); hh.w = h3; ll.w = f2bf(va[3] - bf2f(h3));
          *(ushort4*)(&axh[xr * 72 + xc4]) = hh;
          *(ushort4*)(&axl[xr * 72 + xc4]) = ll;
        }
        *(bf16x8*)(&bwh[wcol * 72 + wc * 8]) = whb;
        *(bf16x8*)(&bwl[wcol * 72 + wc * 8]) = wlb;
        __syncthreads();
        if (it < 3) {  // prefetch next k-chunk (overlaps MFMA)
          xv  = *(const float4*)(x + (size_t)(row0 + xr) * KIN + (it + 1) * 64 + xc4);
          whb = *(const bf16x8*)(whT  + (size_t)wcol * KIN + (it + 1) * 64 + wc * 8);
          wlb = *(const bf16x8*)(wloT + (size_t)wcol * KIN + (it + 1) * 64 + wc * 8);
        }
#pragma unroll
        for (int kk = 0; kk < 2; ++kk) {
          const int kb = kk * 32 + (lane >> 4) * 8;
          const int ar = wm * 16 + (lane & 15);
          const bf16x8 ah = *(const bf16x8*)(&axh[ar * 72 + kb]);
          const bf16x8 al = *(const bf16x8*)(&axl[ar * 72 + kb]);
#pragma unroll
          for (int n = 0; n < 2; ++n) {
            const int cidx = wn * 32 + n * 16 + (lane & 15);
            const bf16x8 bh  = *(const bf16x8*)(&bwh[cidx * 72 + kb]);
            const bf16x8 blo = *(const bf16x8*)(&bwl[cidx * 72 + kb]);
            acc[n] = __builtin_amdgcn_mfma_f32_16x16x32_bf16(ah, bh,  acc[n], 0, 0, 0);
            acc[n] = __builtin_amdgcn_mfma_f32_16x16x32_bf16(ah, blo, acc[n], 0, 0, 0);
            acc[n] = __builtin_amdgcn_mfma_f32_16x16x32_bf16(al, bh,  acc[n], 0, 0, 0);
          }
        }
      }
      needSync = true;
      // epilogue: C map col=lane&15, row=(lane>>4)*4+r
      const int rb = row0 + wm * 16 + (lane >> 4) * 4;
      const int cb = wn * 32 + (lane & 15);
#pragma unroll
      for (int n = 0; n < 2; ++n)
#pragma unroll
        for (int r = 0; r < 4; ++r)
          feats[(size_t)(rb + r) * FO + cb + n * 16] = acc[n][r];
    }
  }
}

// ---------------- Kernel 4a: alpha/beta + kpos/e12 + prefixes (fence-free) --
// grid NB*NCC x 128. Waves 0/1 compute the chunk's 32+32 alpha/beta and the
// chunk rows' kpos/e12 via global binary searches; jidx chunk preloaded into
// LDS in parallel. All 128 threads then do the gather walk.
__global__ __launch_bounds__(128) void k4a_pref(const float* __restrict__ feats,
                                                const float* __restrict__ f1sort,
                                                const float* __restrict__ sc1,
                                                const float* __restrict__ sc2,
                                                const float* __restrict__ f2sort,
                                                const float* __restrict__ f1g,
                                                const int* __restrict__ jidxS,
                                                float2* __restrict__ fineP,
                                                float2* __restrict__ csum,
                                                int* __restrict__ kposA,
                                                float2* __restrict__ e12) {
  __shared__ float sal[64], sbe[64];
  __shared__ int sidx[64];
  const int b = blockIdx.x >> 6, cc = blockIdx.x & 63;
  const int tid = threadIdx.x;
  const int bb = b * NN;
  const int base = bb + cc * 64;

  if (tid < 64) sidx[tid] = jidxS[base + tid];   // preload gather indices

  if (tid < 64) {
    // alpha/beta for sorted-j position pos = cc*64 + tid
    const int pos = cc * 64 + tid;
    const float T1 = sc1[bb + NN - 1];
    const float f1max = f1sort[bb + NN - 1];
    const float f2v = f2sort[bb + pos];
    const float m = f1max + f2v;
    const float M = (m >= 0.f) ? m : SLOPE * m;          // column max of leaky scores
    const int pp = lower_bound_g(f1sort + bb, NN, -f2v); // first i with f1 >= -f2
    const float S1 = T1 - (pp > 0 ? sc1[bb + pp - 1] : 0.f);
    const float S2 = (pp > 0 ? sc2[bb + pp - 1] : 0.f);
    const float ea = expf(f2v - M);
    const float eb = expf(SLOPE * f2v - M);
    const float invD = 1.0f / (ea * S1 + eb * S2);
    sal[tid] = ea * invD;
    sbe[tid] = eb * invD;
  } else {
    // kpos/e12 for row cc*64 + (tid-64)
    const int row = cc * 64 + (tid - 64);
    const float f1v = f1g[bb + row];
    kposA[bb + row] = lower_bound_g(f2sort + bb, NN, -f1v);
    float2 e; e.x = expf(f1v); e.y = expf(SLOPE * f1v);
    e12[bb + row] = e;
  }
  __syncthreads();

  // gather walk: per-position inclusive prefixes + compact chunk total
  const int o = tid;
  const float* fb = feats + (size_t)b * NN * FO;
  float accA = 0.f, accB = 0.f;
#pragma unroll 8
  for (int q = 0; q < 64; ++q) {
    const int kk = base + q;
    const int j = sidx[q];
    const float fv = fb[(size_t)j * FO + o];
    accA = fmaf(sal[q], fv, accA);
    accB = fmaf(sbe[q], fv, accB);
    float2 p; p.x = accA; p.y = accB;
    fineP[(size_t)kk * FO + o] = p;
  }
  float2 cts; cts.x = accA; cts.y = accB;
  csum[(size_t)(b * NCC + cc) * FO + o] = cts;
}

// ---------------- Kernel 4c: exclusive prefix over compact chunk sums -------
__global__ __launch_bounds__(128) void k4c_coar(const float2* __restrict__ csum,
                                                float2* __restrict__ coar) {
  const int b = blockIdx.x;
  const int o = threadIdx.x;
  float runA = 0.f, runB = 0.f;
#pragma unroll
  for (int c = 0; c < NCC; ++c) {
    float2 w; w.x = runA; w.y = runB;
    coar[(size_t)(b * (NCC + 1) + c) * FO + o] = w;
    const float2 v = csum[(size_t)(b * NCC + c) * FO + o];
    runA += v.x; runB += v.y;
  }
  float2 w; w.x = runA; w.y = runB;
  coar[(size_t)(b * (NCC + 1) + NCC) * FO + o] = w;   // total
}

// ---------------- Kernel 5: streaming combine (4 rows per half-block) -------
// grid NROW/8 x 256: half-block h = t>>7 handles rows bid*8 + h*4 .. +3.
__global__ __launch_bounds__(256) void k5_out(const float2* __restrict__ fineP,
                                              const float2* __restrict__ coar,
                                              const int* __restrict__ kposA,
                                              const float2* __restrict__ e12,
                                              float* __restrict__ out) {
  const int t = threadIdx.x;
  const int o = t & 127;
  const int row0 = blockIdx.x * 8 + (t >> 7) * 4;
#pragma unroll
  for (int r = 0; r < 4; ++r) {
    const int row = row0 + r;
    const int b = row >> 12;  // NN = 4096
    const int kp = kposA[row];
    const float2 ev = e12[row];
    const int c = kp >> 6;          // 0..64
    float2 run = coar[(size_t)(b * (NCC + 1) + c) * FO + o];
    const float2 tot = coar[(size_t)(b * (NCC + 1) + NCC) * FO + o];
    if (kp & 63) {
      const float2 f = fineP[(size_t)(b * NN + kp - 1) * FO + o];
      run.x += f.x; run.y += f.y;
    }
    out[(size_t)row * FO + o] = fmaf(ev.x, tot.x - run.x, ev.y * run.y);
  }
}

extern "C" void kernel_launch(void* const* d_in, const int* in_sizes, int n_in,
                              void* d_out, int out_size, void* d_ws, size_t ws_size,
                              hipStream_t stream) {
  const float* x  = (const float*)d_in[0];
  const float* W  = (const float*)d_in[1];
  const float* wl = (const float*)d_in[2];
  const float* bl = (const float*)d_in[3];
  const float* wr = (const float*)d_in[4];
  const float* br = (const float*)d_in[5];
  float* out = (float*)d_out;

  float* ws = (float*)d_ws;
  float* feats    = ws; ws += NROW * FO;
  float2* fineP   = (float2*)ws; ws += NROW * FO * 2;
  float* f1g      = ws; ws += NROW;
  float* f2g      = ws; ws += NROW;
  float* f1sort   = ws; ws += NROW;
  float* f2sort   = ws; ws += NROW;
  float* sc1      = ws; ws += NROW;
  float* sc2      = ws; ws += NROW;
  float2* e12     = (float2*)ws; ws += NROW * 2;
  int* jidxS      = (int*)ws; ws += NROW;
  int* kposA      = (int*)ws; ws += NROW;
  float2* coar    = (float2*)ws; ws += NB * (NCC + 1) * FO * 2;
  float2* csum    = (float2*)ws; ws += NB * NCC * FO * 2;
  u16* whT  = (u16*)ws; ws += FO * KIN / 2;     // bf16 [128 col][256 k]
  u16* wloT = (u16*)ws; ws += FO * KIN / 2;
  (void)in_sizes; (void)n_in; (void)out_size; (void)ws_size;

  hipLaunchKernelGGL(k0_prep,  dim3(NROW / 64), dim3(256),  0, stream,
                     x, W, wl, bl, wr, br, whT, wloT, f1g, f2g);
  hipLaunchKernelGGL(kB_main,  dim3(256),       dim3(1024), 0, stream,
                     x, whT, wloT, f1g, f2g, feats,
                     f1sort, sc1, sc2, f2sort, jidxS);
  hipLaunchKernelGGL(k4a_pref, dim3(NB * NCC),  dim3(128),  0, stream,
                     feats, f1sort, sc1, sc2, f2sort, f1g, jidxS,
                     fineP, csum, kposA, e12);
  hipLaunchKernelGGL(k4c_coar, dim3(NB),        dim3(128),  0, stream,
                     csum, coar);
  hipLaunchKernelGGL(k5_out,   dim3(NROW / 8),  dim3(256),  0, stream,
                     fineP, coar, kposA, e12, out);
}